// Round 20
// baseline (22.906 us; speedup 1.0000x reference)
//
#include <hip/hip_runtime.h>

#define HW       16384                  // 128*128
#define NCLASS   121

// d_out layout (flat f32, return order: pred, m_mask, disappear, appear)
#define OFF_PRED 0
#define OFF_MASK (8 * 3 * HW)                    // 393216
#define OFF_DIS  (OFF_MASK + 8 * NCLASS * HW)    // 16252928
#define OFF_APP  (OFF_DIS + 8 * HW)              // 16384000

#define NSEGBLK  256             // k_seg: per batch, 32 row-tiles (128x4)
#define NPREDBLK 768             // fused: 3 channels x 256 tiles (128x4), FIRST
#define NMASKBLK (8 * NCLASS)    // 968: one block per (batch, channel) PLANE

#define SENT 100000.0f           // OOB sentinel: floor->100000, all targets rejected

typedef float nfloat4 __attribute__((ext_vector_type(4)));

__device__ __forceinline__ float hatf(float u) { return fmaxf(0.f, 1.f - fabsf(u)); }

__device__ __forceinline__ void nt_store4(float* p, float a, float b, float c, float d) {
    nfloat4 nv; nv.x = a; nv.y = b; nv.z = c; nv.w = d;
    __builtin_nontemporal_store(nv, (nfloat4*)p);
}

// K1: seg scatter in LDS for a 128x4 tile -> disappear/appear writes.
__global__ __launch_bounds__(256) void k_seg(const float* __restrict__ motion,
                                             float* __restrict__ out) {
    __shared__ float sseg[4 * 128];     // 2 KB
    int blk = blockIdx.x;               // 0..255
    int b   = blk >> 5;
    int y0  = (blk & 31) << 2;
    int tid = threadIdx.x;

    const float* motx = motion + (size_t)(b * 2) * HW;
    const float* moty = motx + HW;

    float mxv[7], myv[7];
    int   syv[7], sxv[7];
    #pragma unroll
    for (int it = 0; it < 7; ++it) {
        int idx = tid + it * 256;            // 0..1791 -> 14 source rows
        int sy  = y0 - 5 + (idx >> 7);
        int sx  = idx & 127;
        bool ok = (sy >= 0) && (sy < 128);
        int s   = (ok ? sy : 0) * 128 + sx;  // safe fallback address
        float mx = motx[s];
        float my = moty[s];
        mxv[it] = ok ? mx : SENT;
        myv[it] = ok ? my : SENT;
        syv[it] = sy; sxv[it] = sx;
    }

    ((float2*)sseg)[tid] = make_float2(0.f, 0.f);
    __syncthreads();

    #pragma unroll
    for (int it = 0; it < 7; ++it) {
        float mx = mxv[it], my = myv[it];
        int   sy = syv[it], sx = sxv[it];
        float flx = floorf(mx), fly = floorf(my);
        float fa = mx - flx, fb = my - fly;
        int ia = (int)flx + 5, ib = (int)fly + 5;
        float wa0 = 1.f - fa, wa1 = fa;
        float wb0 = 1.f - fb, wb1 = fb;
        #pragma unroll
        for (int j = 0; j < 2; ++j) {
            int ty = sy - (ib + j) + 5;
            if (ty < y0 || ty >= y0 + 4) continue;
            float wb = j ? wb1 : wb0;
            #pragma unroll
            for (int i = 0; i < 2; ++i) {
                int tx = sx - (ia + i) + 5;
                if (tx < 0 || tx >= 128) continue;
                atomicAdd(&sseg[(ty - y0) * 128 + tx], wb * (i ? wa1 : wa0));
            }
        }
    }
    __syncthreads();

    int p2 = tid * 2;
    int ly = p2 >> 7;
    int x  = p2 & 127;
    float2 s2 = *(float2*)&sseg[ly * 128 + x];
    float2 d2, a2;
    d2.x = fmaxf(s2.x - 1.f, 0.f); a2.x = fmaxf(1.f - s2.x, 0.f);
    d2.y = fmaxf(s2.y - 1.f, 0.f); a2.y = fmaxf(1.f - s2.y, 0.f);
    int p = b * HW + (y0 + ly) * 128 + x;
    *(float2*)(out + OFF_DIS + p) = d2;
    *(float2*)(out + OFF_APP + p) = a2;
}

// K2 (fused): blk < NPREDBLK -> pred role (unchanged r13); blk >= NPREDBLK ->
// mask role remapped: ONE (batch, channel) PLANE per block, written
// CONTIGUOUSLY (16 rounds x 4KB NT float4) — fill-kernel-like store walk.
__global__ __launch_bounds__(256) void k_maskpred(const float* __restrict__ motion,
                                                  const float* __restrict__ im_input,
                                                  float* __restrict__ out) {
    __shared__ float spred[4 * 128];    // 2 KB (pred role only)
    int tid = threadIdx.x;
    int blk = blockIdx.x;

    if (blk < NPREDBLK) {
        // ---- pred tile 128x4, channel c ----
        int c  = blk >> 8;               // 0..2
        int t  = blk & 255;
        int b  = t >> 5;
        int y0 = (t & 31) << 2;
        const float* motx = motion + (size_t)(b * 2) * HW;
        const float* moty = motx + HW;
        const float* imc  = im_input + (size_t)(b * 6 + 3 + c) * HW;
        const float* disb = out + OFF_DIS + (size_t)b * HW;

        float mxv[7], myv[7], ivv[7];
        int   syv[7], sxv[7];
        #pragma unroll
        for (int it = 0; it < 7; ++it) {
            int idx = tid + it * 256;        // 0..1791 -> 14 source rows
            int sy  = y0 - 5 + (idx >> 7);
            int sx  = idx & 127;
            bool ok = (sy >= 0) && (sy < 128);
            int s   = (ok ? sy : 0) * 128 + sx;
            float mx = motx[s];
            float my = moty[s];
            float iv = imc[s] * (1.f - disb[s]);
            mxv[it] = ok ? mx : SENT;
            myv[it] = ok ? my : SENT;
            ivv[it] = ok ? iv : 0.f;
            syv[it] = sy; sxv[it] = sx;
        }

        ((float2*)spred)[tid] = make_float2(0.f, 0.f);
        __syncthreads();

        #pragma unroll
        for (int it = 0; it < 7; ++it) {
            float mx = mxv[it], my = myv[it], iv = ivv[it];
            int   sy = syv[it], sx = sxv[it];
            float flx = floorf(mx), fly = floorf(my);
            float fa = mx - flx, fb = my - fly;
            int ia = (int)flx + 5, ib = (int)fly + 5;
            float wa0 = 1.f - fa, wa1 = fa;
            float wb0 = 1.f - fb, wb1 = fb;
            #pragma unroll
            for (int j = 0; j < 2; ++j) {
                int ty = sy - (ib + j) + 5;
                if (ty < y0 || ty >= y0 + 4) continue;
                float wb = j ? wb1 : wb0;
                #pragma unroll
                for (int i = 0; i < 2; ++i) {
                    int tx = sx - (ia + i) + 5;
                    if (tx < 0 || tx >= 128) continue;
                    atomicAdd(&spred[(ty - y0) * 128 + tx], wb * (i ? wa1 : wa0) * iv);
                }
            }
        }
        __syncthreads();

        // store 4 rows x 128 of channel c: 2 px/thread
        int p2 = tid * 2;
        int ly = p2 >> 7;
        int x  = p2 & 127;
        float2 v = *(float2*)&spred[ly * 128 + x];
        float* predb = out + OFF_PRED + (size_t)(b * 3 + c) * HW + (y0 + ly) * 128 + x;
        *(float2*)predb = v;
    } else {
        // ---- mask role: one (b, ch) plane, contiguous NT store walk ----
        int mb = blk - NPREDBLK;         // 0..967
        int b  = mb / NCLASS;
        int ch = mb - b * NCLASS;        // 0..120
        int kb = ch / 11;
        int ka = ch - kb * 11;
        float kao = (float)(ka - 5);
        float kbo = (float)(kb - 5);
        const float* motx = motion + (size_t)(b * 2) * HW;
        const float* moty = motx + HW;
        float* mm = out + OFF_MASK + (size_t)(b * NCLASS + ch) * HW;

        #pragma unroll
        for (int r = 0; r < 16; ++r) {
            int g = (r * 256 + tid) << 2;        // 0..16380, contiguous 4KB/round
            float4 mx = *(const float4*)(motx + g);
            float4 my = *(const float4*)(moty + g);
            nt_store4(mm + g,
                      hatf(my.x - kbo) * hatf(mx.x - kao),
                      hatf(my.y - kbo) * hatf(mx.y - kao),
                      hatf(my.z - kbo) * hatf(mx.z - kao),
                      hatf(my.w - kbo) * hatf(mx.w - kao));
        }
    }
}

extern "C" void kernel_launch(void* const* d_in, const int* in_sizes, int n_in,
                              void* d_out, int out_size, void* d_ws, size_t ws_size,
                              hipStream_t stream) {
    const float* im_input = (const float*)d_in[0];   // (8, 6, 128, 128)
    const float* motion   = (const float*)d_in[1];   // (8, 2, 128, 128)
    // d_in[2] = m_kernel: identity by construction, unused.
    float* out = (float*)d_out;

    k_seg<<<dim3(NSEGBLK), dim3(256), 0, stream>>>(motion, out);
    k_maskpred<<<dim3(NPREDBLK + NMASKBLK), dim3(256), 0, stream>>>(motion, im_input, out);
}

// Round 21
// 21.563 us; speedup vs baseline: 1.0623x; 1.0623x over previous
//
#include <hip/hip_runtime.h>

#define HW       16384                  // 128*128
#define NCLASS   121

// d_out layout (flat f32, return order: pred, m_mask, disappear, appear)
#define OFF_PRED 0
#define OFF_MASK (8 * 3 * HW)                    // 393216
#define OFF_DIS  (OFF_MASK + 8 * NCLASS * HW)    // 16252928
#define OFF_APP  (OFF_DIS + 8 * HW)              // 16384000

#define NSEGBLK  256             // k_seg: per batch, 32 row-tiles (128x4)
#define NPREDBLK 768             // fused: 3 channels x 256 tiles (128x4), FIRST
#define NMASKBLK (8 * 16 * 11)   // 1408: per batch, 16 row-tiles (128x8), 11 kb

#define SENT 100000.0f           // OOB sentinel: floor->100000, all targets rejected

typedef float nfloat4 __attribute__((ext_vector_type(4)));

__device__ __forceinline__ float hatf(float u) { return fmaxf(0.f, 1.f - fabsf(u)); }

__device__ __forceinline__ void nt_store4(float* p, float a, float b, float c, float d) {
    nfloat4 nv; nv.x = a; nv.y = b; nv.z = c; nv.w = d;
    __builtin_nontemporal_store(nv, (nfloat4*)p);
}

// K1: seg scatter in LDS for a 128x4 tile -> disappear/appear writes.
__global__ __launch_bounds__(256) void k_seg(const float* __restrict__ motion,
                                             float* __restrict__ out) {
    __shared__ float sseg[4 * 128];     // 2 KB
    int blk = blockIdx.x;               // 0..255
    int b   = blk >> 5;
    int y0  = (blk & 31) << 2;
    int tid = threadIdx.x;

    const float* motx = motion + (size_t)(b * 2) * HW;
    const float* moty = motx + HW;

    float mxv[7], myv[7];
    #pragma unroll
    for (int it = 0; it < 7; ++it) {
        int idx = tid + it * 256;            // 0..1791 -> 14 source rows
        int sy  = y0 - 5 + (idx >> 7);
        int sx  = idx & 127;
        bool ok = (sy >= 0) && (sy < 128);
        int s   = (ok ? sy : 0) * 128 + sx;  // safe fallback address
        float mx = motx[s];
        float my = moty[s];
        mxv[it] = ok ? mx : SENT;
        myv[it] = ok ? my : SENT;
    }
    asm volatile("" ::: "memory");           // keep loads batched & live here

    ((float2*)sseg)[tid] = make_float2(0.f, 0.f);
    __syncthreads();

    #pragma unroll
    for (int it = 0; it < 7; ++it) {
        int idx = tid + it * 256;
        int sy  = y0 - 5 + (idx >> 7);
        int sx  = idx & 127;
        float mx = mxv[it], my = myv[it];
        float flx = floorf(mx), fly = floorf(my);
        float fa = mx - flx, fb = my - fly;
        int ia = (int)flx + 5, ib = (int)fly + 5;
        float wa0 = 1.f - fa, wa1 = fa;
        float wb0 = 1.f - fb, wb1 = fb;
        #pragma unroll
        for (int j = 0; j < 2; ++j) {
            int ty = sy - (ib + j) + 5;
            if (ty < y0 || ty >= y0 + 4) continue;
            float wb = j ? wb1 : wb0;
            #pragma unroll
            for (int i = 0; i < 2; ++i) {
                int tx = sx - (ia + i) + 5;
                if (tx < 0 || tx >= 128) continue;
                atomicAdd(&sseg[(ty - y0) * 128 + tx], wb * (i ? wa1 : wa0));
            }
        }
    }
    __syncthreads();

    int p2 = tid * 2;
    int ly = p2 >> 7;
    int x  = p2 & 127;
    float2 s2 = *(float2*)&sseg[ly * 128 + x];
    float2 d2, a2;
    d2.x = fmaxf(s2.x - 1.f, 0.f); a2.x = fmaxf(1.f - s2.x, 0.f);
    d2.y = fmaxf(s2.y - 1.f, 0.f); a2.y = fmaxf(1.f - s2.y, 0.f);
    int p = b * HW + (y0 + ly) * 128 + x;
    *(float2*)(out + OFF_DIS + p) = d2;
    *(float2*)(out + OFF_APP + p) = a2;
}

// K2 (fused): blk < NPREDBLK -> pred role, ONE channel per block (batched
// prefetch, dispatched first); blk >= NPREDBLK -> mask role (NT float4 stores).
__global__ __launch_bounds__(256) void k_maskpred(const float* __restrict__ motion,
                                                  const float* __restrict__ im_input,
                                                  float* __restrict__ out) {
    __shared__ float spred[4 * 128];    // 2 KB (pred role only)
    int tid = threadIdx.x;
    int blk = blockIdx.x;

    if (blk < NPREDBLK) {
        // ---- pred tile 128x4, channel c ----
        int c  = blk >> 8;               // 0..2
        int t  = blk & 255;
        int b  = t >> 5;
        int y0 = (t & 31) << 2;
        const float* motx = motion + (size_t)(b * 2) * HW;
        const float* moty = motx + HW;
        const float* imc  = im_input + (size_t)(b * 6 + 3 + c) * HW;
        const float* disb = out + OFF_DIS + (size_t)b * HW;

        float mxv[7], myv[7], imv[7], dsv[7];
        #pragma unroll
        for (int it = 0; it < 7; ++it) {
            int idx = tid + it * 256;        // 0..1791 -> 14 source rows
            int sy  = y0 - 5 + (idx >> 7);
            int sx  = idx & 127;
            bool ok = (sy >= 0) && (sy < 128);
            int s   = (ok ? sy : 0) * 128 + sx;
            float mx = motx[s];
            float my = moty[s];
            float im = imc[s];
            float ds = disb[s];
            mxv[it] = ok ? mx : SENT;
            myv[it] = ok ? my : SENT;
            imv[it] = ok ? im : 0.f;
            dsv[it] = ds;
        }
        asm volatile("" ::: "memory");       // keep loads batched & live here

        ((float2*)spred)[tid] = make_float2(0.f, 0.f);
        __syncthreads();

        #pragma unroll
        for (int it = 0; it < 7; ++it) {
            int idx = tid + it * 256;
            int sy  = y0 - 5 + (idx >> 7);
            int sx  = idx & 127;
            float mx = mxv[it], my = myv[it];
            float iv = imv[it] * (1.f - dsv[it]);
            float flx = floorf(mx), fly = floorf(my);
            float fa = mx - flx, fb = my - fly;
            int ia = (int)flx + 5, ib = (int)fly + 5;
            float wa0 = 1.f - fa, wa1 = fa;
            float wb0 = 1.f - fb, wb1 = fb;
            #pragma unroll
            for (int j = 0; j < 2; ++j) {
                int ty = sy - (ib + j) + 5;
                if (ty < y0 || ty >= y0 + 4) continue;
                float wb = j ? wb1 : wb0;
                #pragma unroll
                for (int i = 0; i < 2; ++i) {
                    int tx = sx - (ia + i) + 5;
                    if (tx < 0 || tx >= 128) continue;
                    atomicAdd(&spred[(ty - y0) * 128 + tx], wb * (i ? wa1 : wa0) * iv);
                }
            }
        }
        __syncthreads();

        // store 4 rows x 128 of channel c: 2 px/thread
        int p2 = tid * 2;
        int ly = p2 >> 7;
        int x  = p2 & 127;
        float2 v = *(float2*)&spred[ly * 128 + x];
        float* predb = out + OFF_PRED + (size_t)(b * 3 + c) * HW + (y0 + ly) * 128 + x;
        *(float2*)predb = v;
    } else {
        // ---- mask role: write m_mask channel-row kb over a 128x8 tile ----
        int mb = blk - NPREDBLK;         // 0..1407
        int kb = mb % 11;
        int tl = mb / 11;                // 0..127
        int b  = tl >> 4;
        int y0 = (tl & 15) << 3;
        const float* motx = motion + (size_t)(b * 2) * HW;
        const float* moty = motx + HW;

        int ly = tid >> 5;               // 0..7
        int x4 = (tid & 31) << 2;        // 0,4,...,124
        int g  = (y0 + ly) * 128 + x4;
        float4 mx = *(const float4*)(motx + g);
        float4 my = *(const float4*)(moty + g);
        float kbo = (float)(kb - 5);
        float4 bv;
        bv.x = hatf(my.x - kbo); bv.y = hatf(my.y - kbo);
        bv.z = hatf(my.z - kbo); bv.w = hatf(my.w - kbo);
        float* mm = out + OFF_MASK + ((size_t)(b * NCLASS + kb * 11)) * HW + g;
        #pragma unroll
        for (int ka = 0; ka < 11; ++ka) {
            float kao = (float)(ka - 5);
            nt_store4(mm + (size_t)ka * HW,
                      bv.x * hatf(mx.x - kao),
                      bv.y * hatf(mx.y - kao),
                      bv.z * hatf(mx.z - kao),
                      bv.w * hatf(mx.w - kao));
        }
    }
}

extern "C" void kernel_launch(void* const* d_in, const int* in_sizes, int n_in,
                              void* d_out, int out_size, void* d_ws, size_t ws_size,
                              hipStream_t stream) {
    const float* im_input = (const float*)d_in[0];   // (8, 6, 128, 128)
    const float* motion   = (const float*)d_in[1];   // (8, 2, 128, 128)
    // d_in[2] = m_kernel: identity by construction, unused.
    float* out = (float*)d_out;

    k_seg<<<dim3(NSEGBLK), dim3(256), 0, stream>>>(motion, out);
    k_maskpred<<<dim3(NPREDBLK + NMASKBLK), dim3(256), 0, stream>>>(motion, im_input, out);
}